// Round 3
// baseline (366.505 us; speedup 1.0000x reference)
//
#include <hip/hip_runtime.h>
#include <math.h>

// LinkedCrossEntropy: mean over B of penalty * weight[y] * NLL
//   B = 65536, C = 1000
//   penalty = 2.0 if (argmax(y_pred[i]) != y_true[i]) && link[y_true[i]][pred] else 1.0
//   NLL = logsumexp(y_pred[i]) - y_pred[i][y_true[i]]
//
// R2 post-mortem: reported dur_us=364 includes ~250us of harness re-poison
// fills / input restore (1GB fillBuffer dispatches @156us dominate rocprof
// top-5; our kernel is <155us). Kernel itself ~110us vs 42us HBM floor.
// R3 restructure: 2 samples/wave-iteration (2x MLP + ILP on shuffle chains),
// max/argmax butterfly BEFORE the exp pass (removes 12 exps + 6 rescale FMAs
// per sample from the dependent chain), scalar s_load epilogue via
// readfirstlane (issued early, off critical path).

#define B_SAMPLES 65536
#define C_CLASSES 1000
#define C4 250  // float4 chunks per row (1000 floats)

__global__ __launch_bounds__(256) void lce_kernel(
    const float* __restrict__ y_pred,
    const int* __restrict__ y_true,
    const float* __restrict__ weight,
    const int* __restrict__ link,  // bool matrix delivered as int32
    float* __restrict__ out)
{
    const int lane = threadIdx.x & 63;
    const int wave = threadIdx.x >> 6;
    const int gwave = blockIdx.x * 4 + wave;
    const int nwaves = gridDim.x * 4;  // 8192

    float local = 0.0f;

    // Two samples per iteration: sA and sB = sA + nwaves. B divisible by
    // 2*nwaves, so no tail (4 iterations of 2 samples per wave).
    for (int s0 = gwave; s0 < B_SAMPLES; s0 += 2 * nwaves) {
        // force SGPR so the epilogue gathers become early scalar loads
        const int sA = __builtin_amdgcn_readfirstlane(s0);
        const int sB = sA + nwaves;

        const int tA = y_true[sA];
        const int tB = y_true[sB];
        const float xtA = y_pred[(size_t)sA * C_CLASSES + tA];
        const float xtB = y_pred[(size_t)sB * C_CLASSES + tB];
        const float wgA = weight[tA];
        const float wgB = weight[tB];

        const float4* rowA = (const float4*)(y_pred + (size_t)sA * C_CLASSES);
        const float4* rowB = (const float4*)(y_pred + (size_t)sB * C_CLASSES);

        // ---- 8 float4 loads in flight (16 elems/lane/sample) ----
        float4 vA[4], vB[4];
        #pragma unroll
        for (int it = 0; it < 4; ++it) {
            int idx = it * 64 + lane;
            if (idx < C4) vA[it] = rowA[idx];
            else vA[it] = make_float4(-INFINITY, -INFINITY, -INFINITY, -INFINITY);
        }
        #pragma unroll
        for (int it = 0; it < 4; ++it) {
            int idx = it * 64 + lane;
            if (idx < C4) vB[it] = rowB[idx];
            else vB[it] = make_float4(-INFINITY, -INFINITY, -INFINITY, -INFINITY);
        }

        // ---- per-lane max + first-occurrence argmax, both samples ----
        float mA = -INFINITY, mB = -INFINITY;
        int amA = 0, amB = 0;
        #pragma unroll
        for (int it = 0; it < 4; ++it) {
            const float* pA = (const float*)&vA[it];
            const float* pB = (const float*)&vB[it];
            #pragma unroll
            for (int j = 0; j < 4; ++j) {
                int col = (it * 64 + lane) * 4 + j;
                if (pA[j] > mA) { mA = pA[j]; amA = col; }
                if (pB[j] > mB) { mB = pB[j]; amB = col; }
            }
        }

        // ---- butterfly max/argmax (no exps on this chain; A/B interleave) ----
        #pragma unroll
        for (int off = 32; off > 0; off >>= 1) {
            float omA = __shfl_xor(mA, off, 64);
            int   oaA = __shfl_xor(amA, off, 64);
            float omB = __shfl_xor(mB, off, 64);
            int   oaB = __shfl_xor(amB, off, 64);
            bool tkA = (omA > mA) || (omA == mA && oaA < amA);
            bool tkB = (omB > mB) || (omB == mB && oaB < amB);
            mA = tkA ? omA : mA;  amA = tkA ? oaA : amA;
            mB = tkB ? omB : mB;  amB = tkB ? oaB : amB;
        }

        // ---- one exp pass with the final max (pad -inf -> exp = 0) ----
        float sumA = 0.0f, sumB = 0.0f;
        #pragma unroll
        for (int it = 0; it < 4; ++it) {
            const float* pA = (const float*)&vA[it];
            const float* pB = (const float*)&vB[it];
            #pragma unroll
            for (int j = 0; j < 4; ++j) {
                sumA += __expf(pA[j] - mA);
                sumB += __expf(pB[j] - mB);
            }
        }

        // ---- pure add butterfly ----
        #pragma unroll
        for (int off = 32; off > 0; off >>= 1) {
            sumA += __shfl_xor(sumA, off, 64);
            sumB += __shfl_xor(sumB, off, 64);
        }

        // ---- uniform epilogue (all lanes identical; link gather scalar) ----
        int amAu = __builtin_amdgcn_readfirstlane(amA);
        int amBu = __builtin_amdgcn_readfirstlane(amB);
        float nllA = mA + __logf(sumA) - xtA;
        float nllB = mB + __logf(sumB) - xtB;
        float penA = (amAu != tA && link[(size_t)tA * C_CLASSES + amAu] != 0) ? 2.0f : 1.0f;
        float penB = (amBu != tB && link[(size_t)tB * C_CLASSES + amBu] != 0) ? 2.0f : 1.0f;
        local += penA * wgA * nllA + penB * wgB * nllB;
    }

    // ---- block reduce (local is wave-uniform; take lane 0 of each wave) ----
    __shared__ float wsum[4];
    if (lane == 0) wsum[wave] = local;
    __syncthreads();
    if (threadIdx.x == 0) {
        float total = (wsum[0] + wsum[1] + wsum[2] + wsum[3]) * (1.0f / B_SAMPLES);
        atomicAdd(out, total);
    }
}

extern "C" void kernel_launch(void* const* d_in, const int* in_sizes, int n_in,
                              void* d_out, int out_size, void* d_ws, size_t ws_size,
                              hipStream_t stream) {
    const float* y_pred = (const float*)d_in[0];
    const int* y_true   = (const int*)d_in[1];
    const float* weight = (const float*)d_in[2];
    const int* link     = (const int*)d_in[3];
    float* out          = (float*)d_out;

    // Harness poisons d_out with 0xAA before every timed launch — zero it.
    hipMemsetAsync(out, 0, sizeof(float), stream);

    // 2048 blocks x 256 threads = 8192 waves -> 8 samples per wave (4 iter x 2).
    lce_kernel<<<2048, 256, 0, stream>>>(y_pred, y_true, weight, link, out);
}